// Round 9
// baseline (586.199 us; speedup 1.0000x reference)
//
#include <hip/hip_runtime.h>
#include <cstdint>
#include <cstddef>

// ---------------- constants ----------------
constexpr int   BB     = 2;
constexpr int   NN     = 2048;
constexpr int   KNB    = 20;      // k nearest neighbors
constexpr float EPS_   = 1e-6f;
constexpr float BNEPS_ = 1e-5f;
constexpr int   KPAD   = 1024;    // padded K for GEMMs (1020 -> 1024)
constexpr int   NTK    = KPAD / 64;   // K-steps per GEMM tile (BK=64)
constexpr int   MT3    = 57;      // Wt3 mtiles (14450 -> 57*256 = 14592)
constexpr int   MPAD3  = MT3 * 256;

typedef __bf16 bf16x8 __attribute__((ext_vector_type(8)));
typedef float  f32x4  __attribute__((ext_vector_type(4)));
typedef float  f32x2  __attribute__((ext_vector_type(2)));
typedef unsigned short u16x8 __attribute__((ext_vector_type(8)));

typedef const void t_gvoid __attribute__((address_space(1)));
typedef void       t_lvoid __attribute__((address_space(3)));

__device__ __forceinline__ unsigned short f2bf(float f) {
  unsigned int u = __builtin_bit_cast(unsigned int, f);
  u += 0x7FFFu + ((u >> 16) & 1u);   // round-to-nearest-even
  return (unsigned short)(u >> 16);
}

// ---------------- KNN: one wave per query ----------------
__global__ __launch_bounds__(256) void knn_kernel(const float* __restrict__ x,
                                                  int* __restrict__ idx) {
  __shared__ float4 pts[NN];                       // x,y,z,|x|^2 : 32 KB
  const int b = blockIdx.x >> 9;
  const int tid = threadIdx.x;
  const float* xb = x + (size_t)b * NN * 3;
  for (int i = tid; i < NN; i += 256) {
    float px = xb[i * 3], py = xb[i * 3 + 1], pz = xb[i * 3 + 2];
    pts[i] = make_float4(px, py, pz, px * px + py * py + pz * pz);
  }
  __syncthreads();
  const int wave = tid >> 6, lane = tid & 63;
  const int q = (blockIdx.x & 511) * 4 + wave;
  const float4 qp = pts[q];

  float d[32];                                     // j = lane + 64*i (static indexing only)
  #pragma unroll
  for (int i = 0; i < 32; ++i) {
    const float4 p = pts[lane + 64 * i];
    d[i] = qp.w + p.w - 2.0f * (qp.x * p.x + qp.y * p.y + qp.z * p.z);
  }

  float m; int mi;
  auto rescan = [&]() {
    m = 3.4e38f; mi = 0;
    #pragma unroll
    for (int i = 0; i < 32; ++i)
      if (d[i] < m) { m = d[i]; mi = i; }          // tie -> smaller i -> smaller j
  };
  rescan();

  int* op = idx + ((size_t)b * NN + q) * KNB;
  for (int r = 0; r < KNB; ++r) {
    float bm = m; int bj = lane + 64 * mi;
    #pragma unroll
    for (int s = 32; s > 0; s >>= 1) {             // wave argmin, lex (d, j)
      const float om = __shfl_xor(bm, s, 64);
      const int   oj = __shfl_xor(bj, s, 64);
      if (om < bm || (om == bm && oj < bj)) { bm = om; bj = oj; }
    }
    if (lane == 0) op[r] = bj;
    if ((bj & 63) == lane) {                       // owner pops its winner, rescans
      const int ii = bj >> 6;
      #pragma unroll
      for (int i = 0; i < 32; ++i)
        if (i == ii) d[i] = 3.4e38f;
      rescan();
    }
  }
}

// ---------------- edge features ----------------
__global__ void feat_kernel(const float* __restrict__ x, const int* __restrict__ idx,
                            float* __restrict__ feat) {
  const int i = blockIdx.x * 256 + threadIdx.x;
  if (i >= BB * NN * KNB) return;
  const int n = (i / KNB) % NN, b = i / (KNB * NN);
  const float* xb = x + (size_t)b * NN * 3;
  const int j = idx[i];
  const float cx = xb[n * 3], cy = xb[n * 3 + 1], cz = xb[n * 3 + 2];
  const float nx = xb[j * 3], ny = xb[j * 3 + 1], nz = xb[j * 3 + 2];
  float* f = feat + (size_t)i * 9;
  f[0] = nx - cx; f[1] = ny - cy; f[2] = nz - cz;
  f[3] = cx;      f[4] = cy;      f[5] = cz;
  f[6] = ny * cz - nz * cy;   // cross(nbr, c)
  f[7] = nz * cx - nx * cz;
  f[8] = nx * cy - ny * cx;
}

// ---------------- layer-1 BN stats: split into (21 ch x 8 chunks) + reduce ----------------
__global__ void l1_stats_part(const float* __restrict__ feat, const float* __restrict__ Wf,
                              float* __restrict__ part) {
  const int o = blockIdx.x, g = blockIdx.y, tid = threadIdx.x;
  const float w0 = Wf[o * 3], w1 = Wf[o * 3 + 1], w2 = Wf[o * 3 + 2];
  const int M = BB * NN * KNB;
  const int chunk = M / 8;
  float s1 = 0.f, s2 = 0.f;
  for (int i = g * chunk + tid; i < (g + 1) * chunk; i += 256) {
    const float* f = feat + (size_t)i * 9;
    float p0 = w0 * f[0] + w1 * f[3] + w2 * f[6];
    float p1 = w0 * f[1] + w1 * f[4] + w2 * f[7];
    float p2 = w0 * f[2] + w1 * f[5] + w2 * f[8];
    float nr = sqrtf(p0 * p0 + p1 * p1 + p2 * p2) + EPS_;
    s1 += nr; s2 += nr * nr;
  }
  __shared__ float rA[256], rB[256];
  rA[tid] = s1; rB[tid] = s2; __syncthreads();
  for (int off = 128; off > 0; off >>= 1) {
    if (tid < off) { rA[tid] += rA[tid + off]; rB[tid] += rB[tid + off]; }
    __syncthreads();
  }
  if (tid == 0) {
    part[(o * 8 + g) * 2]     = rA[0];
    part[(o * 8 + g) * 2 + 1] = rB[0];
  }
}

__global__ void l1_stats_fin(const float* __restrict__ part, const float* __restrict__ gamma,
                             float* __restrict__ stats) {
  const int o = threadIdx.x;
  if (o >= 21) return;
  const int M = BB * NN * KNB;
  float s1 = 0.f, s2 = 0.f;
  for (int g = 0; g < 8; ++g) { s1 += part[(o * 8 + g) * 2]; s2 += part[(o * 8 + g) * 2 + 1]; }
  float mu = s1 / M;
  float var = fmaxf(s2 / M - mu * mu, 0.f);
  stats[2 * o] = mu;
  stats[2 * o + 1] = gamma[o] / sqrtf(var + BNEPS_);
}

// ---------------- layer-1 finalize + mean-pool over k -> h1[b][o][j][n] ----------------
__global__ void l1_final_kernel(const float* __restrict__ feat, const float* __restrict__ Wf,
                                const float* __restrict__ Wd, const float* __restrict__ stats,
                                const float* __restrict__ beta, float* __restrict__ h1) {
  const int o = blockIdx.y, b = blockIdx.z;
  const int n = blockIdx.x * 256 + threadIdx.x;
  const float wf0 = Wf[o * 3], wf1 = Wf[o * 3 + 1], wf2 = Wf[o * 3 + 2];
  const float wd0 = Wd[o * 3], wd1 = Wd[o * 3 + 1], wd2 = Wd[o * 3 + 2];
  const float mu = stats[2 * o], sc = stats[2 * o + 1], be = beta[o];
  const float* fb = feat + ((size_t)(b * NN + n)) * KNB * 9;
  float a0 = 0.f, a1 = 0.f, a2 = 0.f;
  for (int k = 0; k < KNB; ++k) {
    const float* f = fb + k * 9;
    float p0 = wf0 * f[0] + wf1 * f[3] + wf2 * f[6];
    float p1 = wf0 * f[1] + wf1 * f[4] + wf2 * f[7];
    float p2 = wf0 * f[2] + wf1 * f[5] + wf2 * f[8];
    float d0 = wd0 * f[0] + wd1 * f[3] + wd2 * f[6];
    float d1 = wd0 * f[1] + wd1 * f[4] + wd2 * f[7];
    float d2 = wd0 * f[2] + wd1 * f[5] + wd2 * f[8];
    float nr = sqrtf(p0 * p0 + p1 * p1 + p2 * p2) + EPS_;
    float fac = ((nr - mu) * sc + be) / nr;
    p0 *= fac; p1 *= fac; p2 *= fac;
    float dot = p0 * d0 + p1 * d1 + p2 * d2;
    if (dot < 0.f) {                 // ns = 0
      float g = dot / (d0 * d0 + d1 * d1 + d2 * d2 + EPS_);
      p0 -= g * d0; p1 -= g * d1; p2 -= g * d2;
    }
    a0 += p0; a1 += p1; a2 += p2;
  }
  const size_t base = ((size_t)(b * 21 + o) * 3) * NN + n;
  h1[base]          = a0 * (1.f / KNB);
  h1[base + NN]     = a1 * (1.f / KNB);
  h1[base + 2 * NN] = a2 * (1.f / KNB);
}

// ---------------- z-part of the concat layer folded to a per-(b,j,o) bias ----------------
__global__ void zbias_kernel(const float* __restrict__ zbuf, const float* __restrict__ Wf,
                             const float* __restrict__ Wd, float* __restrict__ zbf,
                             float* __restrict__ zbd, int Cout, int CinFull, int Cz) {
  const int bj = blockIdx.x;            // b*3 + j
  const int b = bj / 3, j = bj % 3;
  const int o = threadIdx.x;
  if (o >= Cout) return;
  const int off = CinFull - Cz;
  float sf = 0.f, sd = 0.f;
  for (int cz = 0; cz < Cz; ++cz) {
    const float zv = zbuf[((size_t)b * 170 + cz) * 3 + j];
    sf += Wf[(size_t)o * CinFull + off + cz] * zv;
    sd += Wd[(size_t)o * CinFull + off + cz] * zv;
  }
  zbf[(size_t)bj * Cout + o] = sf;
  zbd[(size_t)bj * Cout + o] = sd;
}

// ---------------- j-fused VN linear + inline BN-stats partials ----------------
// block: (nt: 16 tiles of 128 n) x (ot: 16 channels) x (b). Each thread owns 4 channels
// (og*4+oo) x 2 n (f32x2) x all 3 vector components -> full p-vector in registers, so
// per-channel norm partials (sum, sum^2) are computed inline (wave reduce, 32 chunks/ch).
template <int HAS_D, int CONCAT_Z, int WRITE_STATS>
__global__ __launch_bounds__(256) void vn_lin_fused(
    const float* __restrict__ in, const float* __restrict__ Wf, const float* __restrict__ Wd,
    const float* __restrict__ zbf, const float* __restrict__ zbd,
    float* __restrict__ pout, float* __restrict__ dout, float* __restrict__ bpart,
    int Cin, int CinFull, int Cout) {
  __shared__ float wsh[(HAS_D ? 2 : 1) * 16 * 340];
  float* wfs = wsh;
  float* wds = HAS_D ? (wsh + 16 * 340) : wsh;
  const int tid = threadIdx.x;
  const int nt = blockIdx.x, ot = blockIdx.y, b = blockIdx.z;

  for (int i = tid; i < 16 * Cin; i += 256) {
    const int ol = i / Cin, c = i - ol * Cin;
    const int o = ot * 16 + ol;
    wfs[ol * Cin + c] = (o < Cout) ? Wf[(size_t)o * CinFull + c] : 0.f;
    if (HAS_D) wds[ol * Cin + c] = (o < Cout) ? Wd[(size_t)o * CinFull + c] : 0.f;
  }
  __syncthreads();

  const int lane = tid & 63, og = tid >> 6;
  const int n0 = nt * 128 + lane * 2;
  const float* ibase = in + ((size_t)b * Cin * 3) * NN + n0;

  f32x2 pf[4][3], pd[4][3];
  #pragma unroll
  for (int oo = 0; oo < 4; ++oo)
    #pragma unroll
    for (int j = 0; j < 3; ++j) {
      float bf = 0.f, bd = 0.f;
      if (CONCAT_Z) {
        const int o = ot * 16 + og * 4 + oo;
        if (o < Cout) {
          bf = zbf[(size_t)(b * 3 + j) * Cout + o];
          bd = zbd[(size_t)(b * 3 + j) * Cout + o];
        }
      }
      pf[oo][j] = (f32x2){bf, bf};
      pd[oo][j] = (f32x2){bd, bd};
    }

  #pragma unroll 2
  for (int c = 0; c < Cin; ++c) {
    f32x2 v[3];
    #pragma unroll
    for (int j = 0; j < 3; ++j)
      v[j] = *reinterpret_cast<const f32x2*>(ibase + ((size_t)c * 3 + j) * NN);
    #pragma unroll
    for (int oo = 0; oo < 4; ++oo) {
      const float wf = wfs[(og * 4 + oo) * Cin + c];   // wave-uniform -> LDS broadcast
      #pragma unroll
      for (int j = 0; j < 3; ++j) pf[oo][j] += wf * v[j];
      if (HAS_D) {
        const float wd = wds[(og * 4 + oo) * Cin + c];
        #pragma unroll
        for (int j = 0; j < 3; ++j) pd[oo][j] += wd * v[j];
      }
    }
  }

  #pragma unroll
  for (int oo = 0; oo < 4; ++oo) {
    const int o = ot * 16 + og * 4 + oo;
    if (o < Cout) {
      const size_t ob = ((size_t)(b * Cout + o) * 3) * NN + n0;
      #pragma unroll
      for (int j = 0; j < 3; ++j) {
        *reinterpret_cast<f32x2*>(pout + ob + (size_t)j * NN) = pf[oo][j];
        if (HAS_D) *reinterpret_cast<f32x2*>(dout + ob + (size_t)j * NN) = pd[oo][j];
      }
    }
  }

  if (WRITE_STATS) {
    #pragma unroll
    for (int oo = 0; oo < 4; ++oo) {
      float s1 = 0.f, s2 = 0.f;
      #pragma unroll
      for (int t = 0; t < 2; ++t) {
        const float nr = sqrtf(pf[oo][0][t] * pf[oo][0][t] + pf[oo][1][t] * pf[oo][1][t] +
                               pf[oo][2][t] * pf[oo][2][t]) + EPS_;
        s1 += nr; s2 += nr * nr;
      }
      #pragma unroll
      for (int s = 32; s > 0; s >>= 1) {
        s1 += __shfl_xor(s1, s, 64);
        s2 += __shfl_xor(s2, s, 64);
      }
      const int o = ot * 16 + og * 4 + oo;
      if (lane == 0 && o < Cout) {
        bpart[(o * 32 + b * 16 + nt) * 2]     = s1;
        bpart[(o * 32 + b * 16 + nt) * 2 + 1] = s2;
      }
    }
  }
}

// ---------------- BN apply (+ optional leaky gate), stats reduced inline from partials ----
template <int GATE, int ZPART>
__global__ void vn_gate2(const float* __restrict__ p, const float* __restrict__ d,
                         const float* __restrict__ bpart, const float* __restrict__ gamma,
                         const float* __restrict__ beta, float* __restrict__ out,
                         float* __restrict__ zpart, int Cout, float ns) {
  const int o = blockIdx.y, b = blockIdx.z;
  const int n = blockIdx.x * 256 + threadIdx.x;
  const int M = BB * NN;
  float s1 = 0.f, s2 = 0.f;
  #pragma unroll 8
  for (int i = 0; i < 32; ++i) {                   // deterministic serial reduce
    s1 += bpart[(o * 32 + i) * 2];
    s2 += bpart[(o * 32 + i) * 2 + 1];
  }
  const float mu = s1 / M;
  const float var = fmaxf(s2 / M - mu * mu, 0.f);
  const float sc = gamma[o] / sqrtf(var + BNEPS_);
  const float be = beta[o];

  const size_t base = (((size_t)(b * Cout + o)) * 3) * NN + n;
  float p0 = p[base], p1 = p[base + NN], p2 = p[base + 2 * NN];
  const float nr = sqrtf(p0 * p0 + p1 * p1 + p2 * p2) + EPS_;
  const float fac = ((nr - mu) * sc + be) / nr;
  p0 *= fac; p1 *= fac; p2 *= fac;
  float o0 = p0, o1 = p1, o2 = p2;
  if (GATE) {
    const float d0 = d[base], d1 = d[base + NN], d2 = d[base + 2 * NN];
    const float dot = p0 * d0 + p1 * d1 + p2 * d2;
    if (dot < 0.f) {
      const float g = dot / (d0 * d0 + d1 * d1 + d2 * d2 + EPS_);
      o0 = p0 - g * d0; o1 = p1 - g * d1; o2 = p2 - g * d2;
    }
    o0 = ns * p0 + (1.f - ns) * o0;
    o1 = ns * p1 + (1.f - ns) * o1;
    o2 = ns * p2 + (1.f - ns) * o2;
  }
  out[base] = o0; out[base + NN] = o1; out[base + 2 * NN] = o2;

  if (ZPART) {                                     // z-mean partials (fused zmean)
    float t0 = o0, t1 = o1, t2 = o2;
    #pragma unroll
    for (int s = 32; s > 0; s >>= 1) {
      t0 += __shfl_xor(t0, s, 64);
      t1 += __shfl_xor(t1, s, 64);
      t2 += __shfl_xor(t2, s, 64);
    }
    __shared__ float zsh[3][4];
    const int lane = threadIdx.x & 63, wv = threadIdx.x >> 6;
    if (lane == 0) { zsh[0][wv] = t0; zsh[1][wv] = t1; zsh[2][wv] = t2; }
    __syncthreads();
    if (threadIdx.x < 3) {
      const float s = zsh[threadIdx.x][0] + zsh[threadIdx.x][1] + zsh[threadIdx.x][2] + zsh[threadIdx.x][3];
      zpart[(size_t)(((b * Cout + o) * 3 + threadIdx.x)) * 8 + blockIdx.x] = s;
    }
  }
}

// ---------------- z-mean finalize: reduce 8 zpart chunks -> zbuf + d_out[0:1020] ----------
__global__ void zmean_fin(const float* __restrict__ zpart, float* __restrict__ zbuf,
                          float* __restrict__ outz) {
  const int idx = blockIdx.x * 256 + threadIdx.x;  // b*510 + oj
  if (idx >= BB * 510) return;
  float s = 0.f;
  #pragma unroll
  for (int i = 0; i < 8; ++i) s += zpart[(size_t)idx * 8 + i];
  const float m = s / NN;
  zbuf[idx] = m;
  outz[idx] = m;
}

// ---------------- hs einsum -> t0 bf16, k-major [b][n][kpad] ----------------
__global__ void hs_kernel(const float* __restrict__ h4, const float* __restrict__ zbuf,
                          const float* __restrict__ z0f, unsigned short* __restrict__ t0) {
  const int n = blockIdx.x;
  const int b = blockIdx.z;
  const int tid = threadIdx.x;
  __shared__ float zf[9];
  __shared__ float hcol[512];          // h4[b, oj, n], oj < 510
  __shared__ float zcol[512];          // zbuf[b, oj]
  if (tid < 9) zf[tid] = z0f[(((size_t)(b * 3 + tid / 3)) * 3 + (tid % 3)) * NN + n];
  for (int i = tid; i < 510; i += 256) {
    hcol[i] = h4[((size_t)b * 510 + i) * NN + n];
    zcol[i] = zbuf[(size_t)b * 510 + i];
  }
  __syncthreads();
  unsigned short* trow = t0 + ((size_t)b * NN + n) * KPAD;
  for (int c = tid; c < KPAD; c += 256) {
    if (c >= 1020) { trow[c] = 0; continue; }
    const int i = c / 3, kv = c % 3;
    float acc = 0.f;
    #pragma unroll
    for (int j = 0; j < 3; ++j) {
      const float hv = (i < 170) ? hcol[i * 3 + j] : zcol[(i - 170) * 3 + j];
      acc += hv * zf[j * 3 + kv];
    }
    trow[c] = f2bf(acc);
  }
}

// ---------------- convert + pad weight to bf16 [Mpad][KPAD], 8 elems/thread ----------------
__global__ void wconv_kernel(const float* __restrict__ W, unsigned short* __restrict__ out,
                             int M, int Kv, size_t total8) {
  size_t i = (size_t)blockIdx.x * 256 + threadIdx.x;
  const size_t stride = (size_t)gridDim.x * 256;
  for (; i < total8; i += stride) {
    const size_t e = i * 8;
    const int k = (int)(e & (KPAD - 1));
    const int o = (int)(e >> 10);
    u16x8 v;
    if (o < M && k + 8 <= Kv) {                    // fast path: 2x16B loads, 1x16B store
      const float* src = W + (size_t)o * Kv + k;
      #pragma unroll
      for (int t = 0; t < 8; ++t) v[t] = f2bf(src[t]);
    } else {
      #pragma unroll
      for (int t = 0; t < 8; ++t) {
        const int kk = k + t;
        v[t] = (o < M && kk < Kv) ? f2bf(W[(size_t)o * Kv + kk]) : (unsigned short)0;
      }
    }
    *reinterpret_cast<u16x8*>(out + e) = v;
  }
}

// ---------------- 128x128 bf16 MFMA GEMM (Wt1/Wt2), 1-D grid + chunked XCD swizzle -------
template <int RELU>
__global__ __launch_bounds__(256) void gemm_kernel(
    const unsigned short* __restrict__ A, const unsigned short* __restrict__ Bmat,
    unsigned short* __restrict__ outB, int M) {
  __shared__ __align__(16) unsigned short lA[2][128 * 64];   // 2 x 16 KB
  __shared__ __align__(16) unsigned short lB[2][128 * 64];
  const int tid = threadIdx.x;
  const int nwg = gridDim.x, q = nwg >> 3;         // nwg % 8 == 0 here
  const int orig = blockIdx.x;
  const int swz = (orig & 7) * q + (orig >> 3);    // chunked XCD transform (bijective)
  const int ntile = swz & 15;
  const int mtile = (swz >> 4) & 7;
  const int b = swz >> 7;
  const int lane = tid & 63, w = tid >> 6;
  const int wm = w >> 1, wn = w & 1;
  const int lrow = lane & 15, lgrp = lane >> 4;

  const unsigned short* Abase = A + (size_t)mtile * 128 * KPAD;
  const unsigned short* Bbase = Bmat + ((size_t)b * NN + (size_t)ntile * 128) * KPAD;

  const int rowS = tid >> 3;                       // 0..31
  const int scol = ((tid & 7) * 8) ^ ((rowS & 7) * 8);   // pre-swizzled source col (T2)
  const int wb8  = __builtin_amdgcn_readfirstlane(tid & 192) * 8;

  f32x4 acc[4][4];
  #pragma unroll
  for (int mi = 0; mi < 4; ++mi)
    #pragma unroll
    for (int ni = 0; ni < 4; ++ni) acc[mi][ni] = (f32x4){0.f, 0.f, 0.f, 0.f};

  auto stage = [&](int bufi, int kt) {
    const int kof = kt * 64;
    #pragma unroll
    for (int r = 0; r < 4; ++r) {
      __builtin_amdgcn_global_load_lds(
          (t_gvoid*)(Abase + (size_t)(r * 32 + rowS) * KPAD + kof + scol),
          (t_lvoid*)&lA[bufi][r * 2048 + wb8], 16, 0, 0);
      __builtin_amdgcn_global_load_lds(
          (t_gvoid*)(Bbase + (size_t)(r * 32 + rowS) * KPAD + kof + scol),
          (t_lvoid*)&lB[bufi][r * 2048 + wb8], 16, 0, 0);
    }
  };

  stage(0, 0);
  for (int kt = 0; kt < NTK; ++kt) {
    const int cur = kt & 1;
    if (kt + 1 < NTK) {
      stage(cur ^ 1, kt + 1);
      asm volatile("s_waitcnt vmcnt(8)" ::: "memory");
    } else {
      asm volatile("s_waitcnt vmcnt(0)" ::: "memory");
    }
    asm volatile("s_barrier" ::: "memory");

    bf16x8 af[4][2], bfr[4][2];
    #pragma unroll
    for (int mi = 0; mi < 4; ++mi) {
      const int ra = wm * 64 + mi * 16 + lrow;
      const int rb = wn * 64 + mi * 16 + lrow;
      #pragma unroll
      for (int kk = 0; kk < 2; ++kk) {
        af[mi][kk]  = *reinterpret_cast<const bf16x8*>(
            &lA[cur][ra * 64 + ((kk * 32 + lgrp * 8) ^ ((ra & 7) * 8))]);
        bfr[mi][kk] = *reinterpret_cast<const bf16x8*>(
            &lB[cur][rb * 64 + ((kk * 32 + lgrp * 8) ^ ((rb & 7) * 8))]);
      }
    }
    #pragma unroll
    for (int kk = 0; kk < 2; ++kk)
      #pragma unroll
      for (int mi = 0; mi < 4; ++mi)
        #pragma unroll
        for (int ni = 0; ni < 4; ++ni)
          acc[mi][ni] = __builtin_amdgcn_mfma_f32_16x16x32_bf16(af[mi][kk], bfr[ni][kk],
                                                                acc[mi][ni], 0, 0, 0);
    asm volatile("s_barrier" ::: "memory");
  }

  const int fr_col = lane & 15;
  const int fr_rowb = (lane >> 4) * 4;
  #pragma unroll
  for (int mi = 0; mi < 4; ++mi) {
    const int rowb = mtile * 128 + wm * 64 + mi * 16 + fr_rowb;
    #pragma unroll
    for (int ni = 0; ni < 4; ++ni) {
      const int col = ntile * 128 + wn * 64 + ni * 16 + fr_col;
      ushort4 v;
      if (rowb < M) {
        float u0 = acc[mi][ni][0], u1 = acc[mi][ni][1], u2 = acc[mi][ni][2], u3 = acc[mi][ni][3];
        if (RELU) { u0 = fmaxf(u0, 0.f); u1 = fmaxf(u1, 0.f); u2 = fmaxf(u2, 0.f); u3 = fmaxf(u3, 0.f); }
        v.x = f2bf(u0); v.y = f2bf(u1); v.z = f2bf(u2); v.w = f2bf(u3);
      } else {
        v.x = v.y = v.z = v.w = 0;   // zero pad rows (avoid poison in next GEMM)
      }
      *reinterpret_cast<ushort4*>(outB + ((size_t)b * NN + col) * KPAD + rowb) = v;
    }
  }
}

// ---------------- 256x256 bf16 MFMA GEMM (Wt3), f32 output + bias (proven R5 version) -----
__global__ __launch_bounds__(512, 2) void gemm256_kernel(
    const unsigned short* __restrict__ A, const unsigned short* __restrict__ Bmat,
    float* __restrict__ outF, const float* __restrict__ bias, int M, int MT) {
  __shared__ __align__(16) unsigned short lA[2][256 * 64];   // 2 x 32 KB
  __shared__ __align__(16) unsigned short lB[2][256 * 64];
  const int tid = threadIdx.x;
  const int nwg = gridDim.x, q = nwg >> 3;         // nwg % 8 == 0 (912)
  const int orig = blockIdx.x;
  const int swz = (orig & 7) * q + (orig >> 3);
  const int ntile = swz & 7;                       // NN/256 = 8, fastest
  const int rem = swz >> 3;
  const int mtile = rem % MT;
  const int b = rem / MT;
  const int lane = tid & 63, w = tid >> 6;
  const int wm = w >> 2, wn = w & 3;               // 2 x 4 waves
  const int lrow = lane & 15, lgrp = lane >> 4;

  const unsigned short* Abase = A + (size_t)mtile * 256 * KPAD;
  const unsigned short* Bbase = Bmat + ((size_t)b * NN + (size_t)ntile * 256) * KPAD;

  const int rowS = tid >> 3;                       // 0..63 (row within 64-row round)
  const int scol = ((tid & 7) * 8) ^ ((rowS & 7) * 8);   // pre-swizzled source col (T2)
  const int wb8  = __builtin_amdgcn_readfirstlane((tid & 448) >> 6) * 512; // wave*512 elems

  f32x4 acc[8][4];
  #pragma unroll
  for (int mi = 0; mi < 8; ++mi)
    #pragma unroll
    for (int ni = 0; ni < 4; ++ni) acc[mi][ni] = (f32x4){0.f, 0.f, 0.f, 0.f};

  auto stage = [&](int bufi, int kt) {             // 8 loads/thread = full 256x64 A + B
    const int kof = kt * 64;
    #pragma unroll
    for (int r = 0; r < 4; ++r) {
      __builtin_amdgcn_global_load_lds(
          (t_gvoid*)(Abase + (size_t)(r * 64 + rowS) * KPAD + kof + scol),
          (t_lvoid*)&lA[bufi][r * 4096 + wb8], 16, 0, 0);
      __builtin_amdgcn_global_load_lds(
          (t_gvoid*)(Bbase + (size_t)(r * 64 + rowS) * KPAD + kof + scol),
          (t_lvoid*)&lB[bufi][r * 4096 + wb8], 16, 0, 0);
    }
  };

  stage(0, 0);
  for (int kt = 0; kt < NTK; ++kt) {
    const int cur = kt & 1;
    if (kt + 1 < NTK) {
      stage(cur ^ 1, kt + 1);
      asm volatile("s_waitcnt vmcnt(8)" ::: "memory");
    } else {
      asm volatile("s_waitcnt vmcnt(0)" ::: "memory");
    }
    asm volatile("s_barrier" ::: "memory");

    #pragma unroll
    for (int kk = 0; kk < 2; ++kk) {
      bf16x8 af[8], bfr[4];
      #pragma unroll
      for (int mi = 0; mi < 8; ++mi) {
        const int ra = wm * 128 + mi * 16 + lrow;
        af[mi] = *reinterpret_cast<const bf16x8*>(
            &lA[cur][ra * 64 + ((kk * 32 + lgrp * 8) ^ ((ra & 7) * 8))]);
      }
      #pragma unroll
      for (int ni = 0; ni < 4; ++ni) {
        const int rb = wn * 64 + ni * 16 + lrow;
        bfr[ni] = *reinterpret_cast<const bf16x8*>(
            &lB[cur][rb * 64 + ((kk * 32 + lgrp * 8) ^ ((rb & 7) * 8))]);
      }
      #pragma unroll
      for (int mi = 0; mi < 8; ++mi)
        #pragma unroll
        for (int ni = 0; ni < 4; ++ni)
          acc[mi][ni] = __builtin_amdgcn_mfma_f32_16x16x32_bf16(af[mi], bfr[ni],
                                                                acc[mi][ni], 0, 0, 0);
    }
    asm volatile("s_barrier" ::: "memory");
  }

  const int fr_col = lane & 15;
  const int fr_rowb = (lane >> 4) * 4;
  #pragma unroll
  for (int mi = 0; mi < 8; ++mi) {
    const int rowb = mtile * 256 + wm * 128 + mi * 16 + fr_rowb;
    #pragma unroll
    for (int ni = 0; ni < 4; ++ni) {
      const int col = ntile * 256 + wn * 64 + ni * 16 + fr_col;
      #pragma unroll
      for (int r = 0; r < 4; ++r) {
        const int rr = rowb + r;
        if (rr < M) outF[((size_t)b * M + rr) * NN + col] = acc[mi][ni][r] + bias[rr];
      }
    }
  }
}

// ---------------- launch ----------------
extern "C" void kernel_launch(void* const* d_in, const int* in_sizes, int n_in,
                              void* d_out, int out_size, void* d_ws, size_t ws_size,
                              hipStream_t stream) {
  const float* x      = (const float*)d_in[0];
  const float* Wf_pos = (const float*)d_in[1];
  const float* Wd_pos = (const float*)d_in[2];
  const float* g_pos  = (const float*)d_in[3];
  const float* be_pos = (const float*)d_in[4];
  const float* Wf1    = (const float*)d_in[5];
  const float* Wd1    = (const float*)d_in[6];
  const float* g1     = (const float*)d_in[7];
  const float* be1    = (const float*)d_in[8];
  const float* Wf2    = (const float*)d_in[9];
  const float* Wd2    = (const float*)d_in[10];
  const float* g2     = (const float*)d_in[11];
  const float* be2    = (const float*)d_in[12];
  const float* W3     = (const float*)d_in[13];
  const float* g3     = (const float*)d_in[14];
  const float* be3    = (const float*)d_in[15];
  const float* Ws1f   = (const float*)d_in[16];
  const float* Ws1d   = (const float*)d_in[17];
  const float* gs1    = (const float*)d_in[18];
  const float* bs1    = (const float*)d_in[19];
  const float* Ws2f   = (const float*)d_in[20];
  const float* Ws2d   = (const float*)d_in[21];
  const float* gs2    = (const float*)d_in[22];
  const float* bs2    = (const float*)d_in[23];
  const float* Wstd   = (const float*)d_in[24];
  const float* Wt1    = (const float*)d_in[25];
  const float* Wt2    = (const float*)d_in[26];
  const float* Wt3    = (const float*)d_in[27];
  const float* bt3    = (const float*)d_in[28];
  (void)in_sizes; (void)n_in; (void)out_size; (void)ws_size;

  float* out = (float*)d_out;
  float* out_theta = out + 1020;

  char* ws = (char*)d_ws;
  size_t off = 0;
  auto alloc = [&](size_t bytes) -> void* {
    void* p = (void*)(ws + off);
    off += (bytes + 255) & ~(size_t)255;
    return p;
  };
  int*            idx  = (int*)           alloc((size_t)BB * NN * KNB * 4);
  float*          feat = (float*)         alloc((size_t)BB * NN * KNB * 9 * 4);
  float*          stats= (float*)         alloc(1024 * 4);
  float*          part = (float*)         alloc(2048 * 4);
  float*          bpart= (float*)         alloc((size_t)170 * 32 * 2 * 4);
  float*          zpart= (float*)         alloc((size_t)510 * BB * 8 * 4);
  float*          h1   = (float*)         alloc((size_t)BB * 21 * 3 * NN * 4);
  float*          h2   = (float*)         alloc((size_t)BB * 21 * 3 * NN * 4);
  float*          h3   = (float*)         alloc((size_t)BB * 42 * 3 * NN * 4);
  float*          h4   = (float*)         alloc((size_t)BB * 170 * 3 * NN * 4);
  float*          zbuf = (float*)         alloc((size_t)BB * 170 * 3 * 4);
  float*          pbuf = (float*)         alloc((size_t)BB * 170 * 3 * NN * 4);
  float*          dbuf = (float*)         alloc((size_t)BB * 170 * 3 * NN * 4);
  float*          z0a  = (float*)         alloc((size_t)BB * 170 * 3 * NN * 4);
  float*          z0b  = (float*)         alloc((size_t)BB * 85 * 3 * NN * 4);
  float*          z0f  = (float*)         alloc((size_t)BB * 3 * 3 * NN * 4);
  float*          zbf  = (float*)         alloc((size_t)6 * 170 * 4);
  float*          zbd  = (float*)         alloc((size_t)6 * 170 * 4);
  unsigned short* W1b  = (unsigned short*)alloc((size_t)1024 * KPAD * 2);
  unsigned short* W2b  = (unsigned short*)alloc((size_t)1024 * KPAD * 2);
  unsigned short* W3b  = (unsigned short*)alloc((size_t)MPAD3 * KPAD * 2);
  unsigned short* t0   = (unsigned short*)alloc((size_t)BB * NN * KPAD * 2);
  unsigned short* t1   = (unsigned short*)alloc((size_t)BB * NN * KPAD * 2);
  unsigned short* t2   = t0;   // reuse (t0 dead after GEMM1)

  knn_kernel<<<BB * 512, 256, 0, stream>>>(x, idx);
  feat_kernel<<<(BB * NN * KNB + 255) / 256, 256, 0, stream>>>(x, idx, feat);
  l1_stats_part<<<dim3(21, 8), 256, 0, stream>>>(feat, Wf_pos, part);
  l1_stats_fin<<<1, 64, 0, stream>>>(part, g_pos, stats);
  l1_final_kernel<<<dim3(8, 21, BB), 256, 0, stream>>>(feat, Wf_pos, Wd_pos, stats, be_pos, h1);

  vn_lin_fused<1, 0, 1><<<dim3(16, 2, BB), 256, 0, stream>>>(h1, Wf1, Wd1, nullptr, nullptr, pbuf, dbuf, bpart, 21, 21, 21);
  vn_gate2<1, 0><<<dim3(8, 21, BB), 256, 0, stream>>>(pbuf, dbuf, bpart, g1, be1, h2, nullptr, 21, 0.0f);

  vn_lin_fused<1, 0, 1><<<dim3(16, 3, BB), 256, 0, stream>>>(h2, Wf2, Wd2, nullptr, nullptr, pbuf, dbuf, bpart, 21, 21, 42);
  vn_gate2<1, 0><<<dim3(8, 42, BB), 256, 0, stream>>>(pbuf, dbuf, bpart, g2, be2, h3, nullptr, 42, 0.0f);

  vn_lin_fused<0, 0, 1><<<dim3(16, 11, BB), 256, 0, stream>>>(h3, W3, nullptr, nullptr, nullptr, pbuf, nullptr, bpart, 42, 42, 170);
  vn_gate2<0, 1><<<dim3(8, 170, BB), 256, 0, stream>>>(pbuf, nullptr, bpart, g3, be3, h4, zpart, 170, 0.0f);

  zmean_fin<<<(BB * 510 + 255) / 256, 256, 0, stream>>>(zpart, zbuf, out);

  zbias_kernel<<<6, 256, 0, stream>>>(zbuf, Ws1f, Ws1d, zbf, zbd, 170, 340, 170);
  vn_lin_fused<1, 1, 1><<<dim3(16, 11, BB), 256, 0, stream>>>(h4, Ws1f, Ws1d, zbf, zbd, pbuf, dbuf, bpart, 170, 340, 170);
  vn_gate2<1, 0><<<dim3(8, 170, BB), 256, 0, stream>>>(pbuf, dbuf, bpart, gs1, bs1, z0a, nullptr, 170, 0.2f);

  vn_lin_fused<1, 0, 1><<<dim3(16, 6, BB), 256, 0, stream>>>(z0a, Ws2f, Ws2d, nullptr, nullptr, pbuf, dbuf, bpart, 170, 170, 85);
  vn_gate2<1, 0><<<dim3(8, 85, BB), 256, 0, stream>>>(pbuf, dbuf, bpart, gs2, bs2, z0b, nullptr, 85, 0.2f);

  vn_lin_fused<0, 0, 0><<<dim3(16, 1, BB), 256, 0, stream>>>(z0b, Wstd, nullptr, nullptr, nullptr, z0f, nullptr, nullptr, 85, 85, 3);

  hs_kernel<<<dim3(NN, 1, BB), 256, 0, stream>>>(h4, zbuf, z0f, t0);

  wconv_kernel<<<512, 256, 0, stream>>>(Wt1, W1b, 1020, 1020, (size_t)1024 * KPAD / 8);
  wconv_kernel<<<512, 256, 0, stream>>>(Wt2, W2b, 1020, 1020, (size_t)1024 * KPAD / 8);
  wconv_kernel<<<2048, 256, 0, stream>>>(Wt3, W3b, 14450, 1020, (size_t)MPAD3 * KPAD / 8);

  gemm_kernel<1><<<256, 256, 0, stream>>>(W1b, t0, t1, 1020);
  gemm_kernel<1><<<256, 256, 0, stream>>>(W2b, t1, t2, 1020);
  gemm256_kernel<<<8 * MT3 * BB, 512, 0, stream>>>(W3b, t2, out_theta, bt3, 14450, MT3);
}

// Round 10
// 557.726 us; speedup vs baseline: 1.0511x; 1.0511x over previous
//
#include <hip/hip_runtime.h>
#include <cstdint>
#include <cstddef>

// ---------------- constants ----------------
constexpr int   BB     = 2;
constexpr int   NN     = 2048;
constexpr int   KNB    = 20;      // k nearest neighbors
constexpr float EPS_   = 1e-6f;
constexpr float BNEPS_ = 1e-5f;
constexpr int   KPAD   = 1024;    // padded K for GEMMs (1020 -> 1024)
constexpr int   NTK    = KPAD / 64;   // K-steps per GEMM tile (BK=64)
constexpr int   MT3    = 57;      // Wt3 mtiles (14450 -> 57*256 = 14592)
constexpr int   MPAD3  = MT3 * 256;
constexpr int   HST    = 16;      // hs kernel n-tile

typedef __bf16 bf16x8 __attribute__((ext_vector_type(8)));
typedef float  f32x4  __attribute__((ext_vector_type(4)));
typedef unsigned short u16x8 __attribute__((ext_vector_type(8)));

typedef const void t_gvoid __attribute__((address_space(1)));
typedef void       t_lvoid __attribute__((address_space(3)));

__device__ __forceinline__ unsigned short f2bf(float f) {
  unsigned int u = __builtin_bit_cast(unsigned int, f);
  u += 0x7FFFu + ((u >> 16) & 1u);   // round-to-nearest-even
  return (unsigned short)(u >> 16);
}

// ---------------- KNN: one wave per query ----------------
__global__ __launch_bounds__(256) void knn_kernel(const float* __restrict__ x,
                                                  int* __restrict__ idx) {
  __shared__ float4 pts[NN];                       // x,y,z,|x|^2 : 32 KB
  const int b = blockIdx.x >> 9;
  const int tid = threadIdx.x;
  const float* xb = x + (size_t)b * NN * 3;
  for (int i = tid; i < NN; i += 256) {
    float px = xb[i * 3], py = xb[i * 3 + 1], pz = xb[i * 3 + 2];
    pts[i] = make_float4(px, py, pz, px * px + py * py + pz * pz);
  }
  __syncthreads();
  const int wave = tid >> 6, lane = tid & 63;
  const int q = (blockIdx.x & 511) * 4 + wave;
  const float4 qp = pts[q];

  float d[32];                                     // j = lane + 64*i (static indexing only)
  #pragma unroll
  for (int i = 0; i < 32; ++i) {
    const float4 p = pts[lane + 64 * i];
    d[i] = qp.w + p.w - 2.0f * (qp.x * p.x + qp.y * p.y + qp.z * p.z);
  }

  float m; int mi;
  auto rescan = [&]() {
    m = 3.4e38f; mi = 0;
    #pragma unroll
    for (int i = 0; i < 32; ++i)
      if (d[i] < m) { m = d[i]; mi = i; }          // tie -> smaller i -> smaller j
  };
  rescan();

  int* op = idx + ((size_t)b * NN + q) * KNB;
  for (int r = 0; r < KNB; ++r) {
    float bm = m; int bj = lane + 64 * mi;
    #pragma unroll
    for (int s = 32; s > 0; s >>= 1) {             // wave argmin, lex (d, j)
      const float om = __shfl_xor(bm, s, 64);
      const int   oj = __shfl_xor(bj, s, 64);
      if (om < bm || (om == bm && oj < bj)) { bm = om; bj = oj; }
    }
    if (lane == 0) op[r] = bj;
    if ((bj & 63) == lane) {                       // owner pops its winner, rescans
      const int ii = bj >> 6;
      #pragma unroll
      for (int i = 0; i < 32; ++i)
        if (i == ii) d[i] = 3.4e38f;
      rescan();
    }
  }
}

// ---------------- edge features ----------------
__global__ void feat_kernel(const float* __restrict__ x, const int* __restrict__ idx,
                            float* __restrict__ feat) {
  const int i = blockIdx.x * 256 + threadIdx.x;
  if (i >= BB * NN * KNB) return;
  const int n = (i / KNB) % NN, b = i / (KNB * NN);
  const float* xb = x + (size_t)b * NN * 3;
  const int j = idx[i];
  const float cx = xb[n * 3], cy = xb[n * 3 + 1], cz = xb[n * 3 + 2];
  const float nx = xb[j * 3], ny = xb[j * 3 + 1], nz = xb[j * 3 + 2];
  float* f = feat + (size_t)i * 9;
  f[0] = nx - cx; f[1] = ny - cy; f[2] = nz - cz;
  f[3] = cx;      f[4] = cy;      f[5] = cz;
  f[6] = ny * cz - nz * cy;   // cross(nbr, c)
  f[7] = nz * cx - nx * cz;
  f[8] = nx * cy - ny * cx;
}

// ---------------- layer-1 BN stats: split into (21 ch x 8 chunks) + reduce ----------------
__global__ void l1_stats_part(const float* __restrict__ feat, const float* __restrict__ Wf,
                              float* __restrict__ part) {
  const int o = blockIdx.x, g = blockIdx.y, tid = threadIdx.x;
  const float w0 = Wf[o * 3], w1 = Wf[o * 3 + 1], w2 = Wf[o * 3 + 2];
  const int M = BB * NN * KNB;
  const int chunk = M / 8;
  float s1 = 0.f, s2 = 0.f;
  for (int i = g * chunk + tid; i < (g + 1) * chunk; i += 256) {
    const float* f = feat + (size_t)i * 9;
    float p0 = w0 * f[0] + w1 * f[3] + w2 * f[6];
    float p1 = w0 * f[1] + w1 * f[4] + w2 * f[7];
    float p2 = w0 * f[2] + w1 * f[5] + w2 * f[8];
    float nr = sqrtf(p0 * p0 + p1 * p1 + p2 * p2) + EPS_;
    s1 += nr; s2 += nr * nr;
  }
  __shared__ float rA[256], rB[256];
  rA[tid] = s1; rB[tid] = s2; __syncthreads();
  for (int off = 128; off > 0; off >>= 1) {
    if (tid < off) { rA[tid] += rA[tid + off]; rB[tid] += rB[tid + off]; }
    __syncthreads();
  }
  if (tid == 0) {
    part[(o * 8 + g) * 2]     = rA[0];
    part[(o * 8 + g) * 2 + 1] = rB[0];
  }
}

__global__ void l1_stats_fin(const float* __restrict__ part, const float* __restrict__ gamma,
                             float* __restrict__ stats) {
  const int o = threadIdx.x;
  if (o >= 21) return;
  const int M = BB * NN * KNB;
  float s1 = 0.f, s2 = 0.f;
  for (int g = 0; g < 8; ++g) { s1 += part[(o * 8 + g) * 2]; s2 += part[(o * 8 + g) * 2 + 1]; }
  float mu = s1 / M;
  float var = fmaxf(s2 / M - mu * mu, 0.f);
  stats[2 * o] = mu;
  stats[2 * o + 1] = gamma[o] / sqrtf(var + BNEPS_);
}

// ---------------- layer-1 finalize + mean-pool over k -> h1[b][o][j][n] ----------------
__global__ void l1_final_kernel(const float* __restrict__ feat, const float* __restrict__ Wf,
                                const float* __restrict__ Wd, const float* __restrict__ stats,
                                const float* __restrict__ beta, float* __restrict__ h1) {
  const int o = blockIdx.y, b = blockIdx.z;
  const int n = blockIdx.x * 256 + threadIdx.x;
  const float wf0 = Wf[o * 3], wf1 = Wf[o * 3 + 1], wf2 = Wf[o * 3 + 2];
  const float wd0 = Wd[o * 3], wd1 = Wd[o * 3 + 1], wd2 = Wd[o * 3 + 2];
  const float mu = stats[2 * o], sc = stats[2 * o + 1], be = beta[o];
  const float* fb = feat + ((size_t)(b * NN + n)) * KNB * 9;
  float a0 = 0.f, a1 = 0.f, a2 = 0.f;
  for (int k = 0; k < KNB; ++k) {
    const float* f = fb + k * 9;
    float p0 = wf0 * f[0] + wf1 * f[3] + wf2 * f[6];
    float p1 = wf0 * f[1] + wf1 * f[4] + wf2 * f[7];
    float p2 = wf0 * f[2] + wf1 * f[5] + wf2 * f[8];
    float d0 = wd0 * f[0] + wd1 * f[3] + wd2 * f[6];
    float d1 = wd0 * f[1] + wd1 * f[4] + wd2 * f[7];
    float d2 = wd0 * f[2] + wd1 * f[5] + wd2 * f[8];
    float nr = sqrtf(p0 * p0 + p1 * p1 + p2 * p2) + EPS_;
    float fac = ((nr - mu) * sc + be) / nr;
    p0 *= fac; p1 *= fac; p2 *= fac;
    float dot = p0 * d0 + p1 * d1 + p2 * d2;
    if (dot < 0.f) {                 // ns = 0
      float g = dot / (d0 * d0 + d1 * d1 + d2 * d2 + EPS_);
      p0 -= g * d0; p1 -= g * d1; p2 -= g * d2;
    }
    a0 += p0; a1 += p1; a2 += p2;
  }
  const size_t base = ((size_t)(b * 21 + o) * 3) * NN + n;
  h1[base]          = a0 * (1.f / KNB);
  h1[base + NN]     = a1 * (1.f / KNB);
  h1[base + 2 * NN] = a2 * (1.f / KNB);
}

// ---------------- z-part of the concat layer folded to a per-(b,j,o) bias ----------------
__global__ void zbias_kernel(const float* __restrict__ zbuf, const float* __restrict__ Wf,
                             const float* __restrict__ Wd, float* __restrict__ zbf,
                             float* __restrict__ zbd, int Cout, int CinFull, int Cz) {
  const int bj = blockIdx.x;            // b*3 + j
  const int b = bj / 3, j = bj % 3;
  const int o = threadIdx.x;
  if (o >= Cout) return;
  const int off = CinFull - Cz;
  float sf = 0.f, sd = 0.f;
  for (int cz = 0; cz < Cz; ++cz) {
    const float zv = zbuf[((size_t)b * 170 + cz) * 3 + j];
    sf += Wf[(size_t)o * CinFull + off + cz] * zv;
    sd += Wd[(size_t)o * CinFull + off + cz] * zv;
  }
  zbf[(size_t)bj * Cout + o] = sf;
  zbd[(size_t)bj * Cout + o] = sd;
}

// ---------------- register-blocked VN linear ----------------
template <int HAS_D, int CONCAT_Z>
__global__ __launch_bounds__(256) void vn_lin_fast(
    const float* __restrict__ in, const float* __restrict__ Wf, const float* __restrict__ Wd,
    const float* __restrict__ zbf, const float* __restrict__ zbd,
    float* __restrict__ pout, float* __restrict__ dout,
    int Cin, int CinFull, int Cout) {
  __shared__ float wsh[(HAS_D ? 2 : 1) * 16 * 340];
  float* wfs = wsh;
  float* wds = HAS_D ? (wsh + 16 * 340) : wsh;
  const int tid = threadIdx.x;
  const int nt = blockIdx.x, ot = blockIdx.y;
  const int b = blockIdx.z / 3, j = blockIdx.z % 3;

  for (int i = tid; i < 16 * Cin; i += 256) {
    const int ol = i / Cin, c = i - ol * Cin;
    const int o = ot * 16 + ol;
    wfs[ol * Cin + c] = (o < Cout) ? Wf[(size_t)o * CinFull + c] : 0.f;
    if (HAS_D) wds[ol * Cin + c] = (o < Cout) ? Wd[(size_t)o * CinFull + c] : 0.f;
  }
  __syncthreads();

  const int lane = tid & 63, og = tid >> 6;
  const int n0 = nt * 256 + lane * 4;
  const float* ibase = in + ((size_t)b * Cin * 3 + j) * NN + n0;

  f32x4 accf[4], accd[4];
  #pragma unroll
  for (int oo = 0; oo < 4; ++oo) {
    float bf = 0.f, bd = 0.f;
    if (CONCAT_Z) {
      const int o = ot * 16 + og * 4 + oo;
      if (o < Cout) {
        bf = zbf[(size_t)blockIdx.z * Cout + o];
        bd = zbd[(size_t)blockIdx.z * Cout + o];
      }
    }
    accf[oo] = (f32x4){bf, bf, bf, bf};
    accd[oo] = (f32x4){bd, bd, bd, bd};
  }

  #pragma unroll 4
  for (int c = 0; c < Cin; ++c) {
    const f32x4 v = *reinterpret_cast<const f32x4*>(ibase + (size_t)c * 3 * NN);
    #pragma unroll
    for (int oo = 0; oo < 4; ++oo) {
      const float wf = wfs[(og * 4 + oo) * Cin + c];   // wave-uniform -> LDS broadcast
      accf[oo] += wf * v;
      if (HAS_D) {
        const float wd = wds[(og * 4 + oo) * Cin + c];
        accd[oo] += wd * v;
      }
    }
  }

  #pragma unroll
  for (int oo = 0; oo < 4; ++oo) {
    const int o = ot * 16 + og * 4 + oo;
    if (o < Cout) {
      const size_t ob = ((size_t)(b * Cout + o) * 3 + j) * NN + n0;
      *reinterpret_cast<f32x4*>(pout + ob) = accf[oo];
      if (HAS_D) *reinterpret_cast<f32x4*>(dout + ob) = accd[oo];
    }
  }
}

// ---------------- generic BN stats over (B,N): one block per channel ----------------
__global__ void bn_stats_kernel(const float* __restrict__ p, const float* __restrict__ gamma,
                                float* __restrict__ stats, int Cout) {
  const int o = blockIdx.x, tid = threadIdx.x;
  const int M = BB * NN;
  float s1 = 0.f, s2 = 0.f;
  for (int i = tid; i < M; i += 256) {
    const int b = i >> 11, n = i & (NN - 1);
    const size_t base = (((size_t)(b * Cout + o)) * 3) * NN + n;
    float p0 = p[base], p1 = p[base + NN], p2 = p[base + 2 * NN];
    float nr = sqrtf(p0 * p0 + p1 * p1 + p2 * p2) + EPS_;
    s1 += nr; s2 += nr * nr;
  }
  __shared__ float rA[256], rB[256];
  rA[tid] = s1; rB[tid] = s2; __syncthreads();
  for (int off = 128; off > 0; off >>= 1) {
    if (tid < off) { rA[tid] += rA[tid + off]; rB[tid] += rB[tid + off]; }
    __syncthreads();
  }
  if (tid == 0) {
    float mu = rA[0] / M;
    float var = fmaxf(rB[0] / M - mu * mu, 0.f);
    stats[2 * o] = mu;
    stats[2 * o + 1] = gamma[o] / sqrtf(var + BNEPS_);
  }
}

// ---------------- BN apply (+ optional leaky gate) ----------------
template <int GATE>
__global__ void vn_gate_kernel(const float* __restrict__ p, const float* __restrict__ d,
                               const float* __restrict__ stats, const float* __restrict__ beta,
                               float* __restrict__ out, int Cout, float ns) {
  const int o = blockIdx.y, b = blockIdx.z;
  const int n = blockIdx.x * 256 + threadIdx.x;
  const size_t base = (((size_t)(b * Cout + o)) * 3) * NN + n;
  float p0 = p[base], p1 = p[base + NN], p2 = p[base + 2 * NN];
  const float nr = sqrtf(p0 * p0 + p1 * p1 + p2 * p2) + EPS_;
  const float fac = ((nr - stats[2 * o]) * stats[2 * o + 1] + beta[o]) / nr;
  p0 *= fac; p1 *= fac; p2 *= fac;
  float o0 = p0, o1 = p1, o2 = p2;
  if (GATE) {
    const float d0 = d[base], d1 = d[base + NN], d2 = d[base + 2 * NN];
    const float dot = p0 * d0 + p1 * d1 + p2 * d2;
    if (dot < 0.f) {
      const float g = dot / (d0 * d0 + d1 * d1 + d2 * d2 + EPS_);
      o0 = p0 - g * d0; o1 = p1 - g * d1; o2 = p2 - g * d2;
    }
    o0 = ns * p0 + (1.f - ns) * o0;
    o1 = ns * p1 + (1.f - ns) * o1;
    o2 = ns * p2 + (1.f - ns) * o2;
  }
  out[base] = o0; out[base + NN] = o1; out[base + 2 * NN] = o2;
}

// ---------------- z = mean over n of h4 ----------------
__global__ void zmean_kernel(const float* __restrict__ h4, float* __restrict__ zbuf,
                             float* __restrict__ outz) {
  const int oj = blockIdx.x;           // 0..509 = o*3+j
  const int b = blockIdx.y;
  const int tid = threadIdx.x;
  const float* src = h4 + ((size_t)b * 510 + oj) * NN;
  float s = 0.f;
  for (int n = tid; n < NN; n += 256) s += src[n];
  __shared__ float r[256];
  r[tid] = s; __syncthreads();
  for (int off = 128; off > 0; off >>= 1) {
    if (tid < off) r[tid] += r[tid + off];
    __syncthreads();
  }
  if (tid == 0) {
    float m = r[0] / NN;
    zbuf[(size_t)b * 510 + oj] = m;
    outz[(size_t)b * 510 + oj] = m;
  }
}

// ---------------- hs einsum -> t0 bf16, k-major [b][n][kpad] ----------------
// block = (b, 16-n tile): stage h4[:, n0:n0+16] via coalesced 64B rows (each element
// fetched once), pad LDS stride to 17 (oj*16 would alias 2 banks 32-way). Compute:
// wave owns 4 n-columns, lanes sweep 64 consecutive c -> 128B contiguous bf16 stores.
__global__ __launch_bounds__(256) void hs_kernel(const float* __restrict__ h4,
                                                 const float* __restrict__ zbuf,
                                                 const float* __restrict__ z0f,
                                                 unsigned short* __restrict__ t0) {
  const int n0 = blockIdx.x * HST;
  const int b = blockIdx.z;
  const int tid = threadIdx.x;
  __shared__ float hcol[510 * (HST + 1)];          // [oj][nl], stride 17
  __shared__ float zcol[510];
  __shared__ float zf[9 * HST];                    // [j*3+kv][nl]
  for (int i = tid; i < 510; i += 256) zcol[i] = zbuf[(size_t)b * 510 + i];
  if (tid < 9 * HST) {
    const int jk = tid / HST, nl = tid % HST;
    zf[jk * HST + nl] = z0f[((size_t)(b * 9) + jk) * NN + n0 + nl];
  }
  const int nl = tid & (HST - 1);
  for (int i = tid / HST; i < 510; i += 256 / HST) {
    hcol[i * (HST + 1) + nl] = h4[((size_t)b * 510 + i) * NN + n0 + nl];
  }
  __syncthreads();

  const int lane = tid & 63, w = tid >> 6;
  unsigned short* tbase = t0 + ((size_t)b * NN + n0) * KPAD;
  for (int nn = 0; nn < HST / 4; ++nn) {
    const int nc = w * (HST / 4) + nn;             // this wave's n-column
    unsigned short* trow = tbase + (size_t)nc * KPAD;
    for (int cc = 0; cc < KPAD / 64; ++cc) {
      const int c = cc * 64 + lane;
      float acc = 0.f;
      if (c < 1020) {
        const int i = c / 3, kv = c - i * 3;
        #pragma unroll
        for (int j = 0; j < 3; ++j) {
          const float hv = (i < 170) ? hcol[(i * 3 + j) * (HST + 1) + nc]
                                     : zcol[(i - 170) * 3 + j];
          acc += hv * zf[(j * 3 + kv) * HST + nc];
        }
      }
      trow[c] = f2bf(acc);
    }
  }
}

// ---------------- convert + pad weight to bf16 [Mpad][KPAD], 8 elems/thread ----------------
__global__ void wconv_kernel(const float* __restrict__ W, unsigned short* __restrict__ out,
                             int M, int Kv, size_t total8) {
  size_t i = (size_t)blockIdx.x * 256 + threadIdx.x;
  const size_t stride = (size_t)gridDim.x * 256;
  for (; i < total8; i += stride) {
    const size_t e = i * 8;
    const int k = (int)(e & (KPAD - 1));
    const int o = (int)(e >> 10);
    u16x8 v;
    if (o < M && k + 8 <= Kv) {                    // fast path: 2x16B loads, 1x16B store
      const float* src = W + (size_t)o * Kv + k;
      #pragma unroll
      for (int t = 0; t < 8; ++t) v[t] = f2bf(src[t]);
    } else {
      #pragma unroll
      for (int t = 0; t < 8; ++t) {
        const int kk = k + t;
        v[t] = (o < M && kk < Kv) ? f2bf(W[(size_t)o * Kv + kk]) : (unsigned short)0;
      }
    }
    *reinterpret_cast<u16x8*>(out + e) = v;
  }
}

// ---------------- 128x128 bf16 MFMA GEMM (Wt1/Wt2), 1-D grid + chunked XCD swizzle -------
template <int RELU>
__global__ __launch_bounds__(256) void gemm_kernel(
    const unsigned short* __restrict__ A, const unsigned short* __restrict__ Bmat,
    unsigned short* __restrict__ outB, int M) {
  __shared__ __align__(16) unsigned short lA[2][128 * 64];   // 2 x 16 KB
  __shared__ __align__(16) unsigned short lB[2][128 * 64];
  const int tid = threadIdx.x;
  const int nwg = gridDim.x, q = nwg >> 3;         // nwg % 8 == 0 here
  const int orig = blockIdx.x;
  const int swz = (orig & 7) * q + (orig >> 3);    // chunked XCD transform (bijective)
  const int ntile = swz & 15;
  const int mtile = (swz >> 4) & 7;
  const int b = swz >> 7;
  const int lane = tid & 63, w = tid >> 6;
  const int wm = w >> 1, wn = w & 1;
  const int lrow = lane & 15, lgrp = lane >> 4;

  const unsigned short* Abase = A + (size_t)mtile * 128 * KPAD;
  const unsigned short* Bbase = Bmat + ((size_t)b * NN + (size_t)ntile * 128) * KPAD;

  const int rowS = tid >> 3;                       // 0..31
  const int scol = ((tid & 7) * 8) ^ ((rowS & 7) * 8);   // pre-swizzled source col (T2)
  const int wb8  = __builtin_amdgcn_readfirstlane(tid & 192) * 8;

  f32x4 acc[4][4];
  #pragma unroll
  for (int mi = 0; mi < 4; ++mi)
    #pragma unroll
    for (int ni = 0; ni < 4; ++ni) acc[mi][ni] = (f32x4){0.f, 0.f, 0.f, 0.f};

  auto stage = [&](int bufi, int kt) {
    const int kof = kt * 64;
    #pragma unroll
    for (int r = 0; r < 4; ++r) {
      __builtin_amdgcn_global_load_lds(
          (t_gvoid*)(Abase + (size_t)(r * 32 + rowS) * KPAD + kof + scol),
          (t_lvoid*)&lA[bufi][r * 2048 + wb8], 16, 0, 0);
      __builtin_amdgcn_global_load_lds(
          (t_gvoid*)(Bbase + (size_t)(r * 32 + rowS) * KPAD + kof + scol),
          (t_lvoid*)&lB[bufi][r * 2048 + wb8], 16, 0, 0);
    }
  };

  stage(0, 0);
  for (int kt = 0; kt < NTK; ++kt) {
    const int cur = kt & 1;
    if (kt + 1 < NTK) {
      stage(cur ^ 1, kt + 1);
      asm volatile("s_waitcnt vmcnt(8)" ::: "memory");
    } else {
      asm volatile("s_waitcnt vmcnt(0)" ::: "memory");
    }
    asm volatile("s_barrier" ::: "memory");

    bf16x8 af[4][2], bfr[4][2];
    #pragma unroll
    for (int mi = 0; mi < 4; ++mi) {
      const int ra = wm * 64 + mi * 16 + lrow;
      const int rb = wn * 64 + mi * 16 + lrow;
      #pragma unroll
      for (int kk = 0; kk < 2; ++kk) {
        af[mi][kk]  = *reinterpret_cast<const bf16x8*>(
            &lA[cur][ra * 64 + ((kk * 32 + lgrp * 8) ^ ((ra & 7) * 8))]);
        bfr[mi][kk] = *reinterpret_cast<const bf16x8*>(
            &lB[cur][rb * 64 + ((kk * 32 + lgrp * 8) ^ ((rb & 7) * 8))]);
      }
    }
    #pragma unroll
    for (int kk = 0; kk < 2; ++kk)
      #pragma unroll
      for (int mi = 0; mi < 4; ++mi)
        #pragma unroll
        for (int ni = 0; ni < 4; ++ni)
          acc[mi][ni] = __builtin_amdgcn_mfma_f32_16x16x32_bf16(af[mi][kk], bfr[ni][kk],
                                                                acc[mi][ni], 0, 0, 0);
    asm volatile("s_barrier" ::: "memory");
  }

  const int fr_col = lane & 15;
  const int fr_rowb = (lane >> 4) * 4;
  #pragma unroll
  for (int mi = 0; mi < 4; ++mi) {
    const int rowb = mtile * 128 + wm * 64 + mi * 16 + fr_rowb;
    #pragma unroll
    for (int ni = 0; ni < 4; ++ni) {
      const int col = ntile * 128 + wn * 64 + ni * 16 + fr_col;
      ushort4 v;
      if (rowb < M) {
        float u0 = acc[mi][ni][0], u1 = acc[mi][ni][1], u2 = acc[mi][ni][2], u3 = acc[mi][ni][3];
        if (RELU) { u0 = fmaxf(u0, 0.f); u1 = fmaxf(u1, 0.f); u2 = fmaxf(u2, 0.f); u3 = fmaxf(u3, 0.f); }
        v.x = f2bf(u0); v.y = f2bf(u1); v.z = f2bf(u2); v.w = f2bf(u3);
      } else {
        v.x = v.y = v.z = v.w = 0;   // zero pad rows (avoid poison in next GEMM)
      }
      *reinterpret_cast<ushort4*>(outB + ((size_t)b * NN + col) * KPAD + rowb) = v;
    }
  }
}

// ---------------- 256x256 bf16 MFMA GEMM (Wt3), f32 output + bias (proven R5 version) -----
__global__ __launch_bounds__(512, 2) void gemm256_kernel(
    const unsigned short* __restrict__ A, const unsigned short* __restrict__ Bmat,
    float* __restrict__ outF, const float* __restrict__ bias, int M, int MT) {
  __shared__ __align__(16) unsigned short lA[2][256 * 64];   // 2 x 32 KB
  __shared__ __align__(16) unsigned short lB[2][256 * 64];
  const int tid = threadIdx.x;
  const int nwg = gridDim.x, q = nwg >> 3;         // nwg % 8 == 0 (912)
  const int orig = blockIdx.x;
  const int swz = (orig & 7) * q + (orig >> 3);
  const int ntile = swz & 7;                       // NN/256 = 8, fastest
  const int rem = swz >> 3;
  const int mtile = rem % MT;
  const int b = rem / MT;
  const int lane = tid & 63, w = tid >> 6;
  const int wm = w >> 2, wn = w & 3;               // 2 x 4 waves
  const int lrow = lane & 15, lgrp = lane >> 4;

  const unsigned short* Abase = A + (size_t)mtile * 256 * KPAD;
  const unsigned short* Bbase = Bmat + ((size_t)b * NN + (size_t)ntile * 256) * KPAD;

  const int rowS = tid >> 3;                       // 0..63 (row within 64-row round)
  const int scol = ((tid & 7) * 8) ^ ((rowS & 7) * 8);   // pre-swizzled source col (T2)
  const int wb8  = __builtin_amdgcn_readfirstlane((tid & 448) >> 6) * 512; // wave*512 elems

  f32x4 acc[8][4];
  #pragma unroll
  for (int mi = 0; mi < 8; ++mi)
    #pragma unroll
    for (int ni = 0; ni < 4; ++ni) acc[mi][ni] = (f32x4){0.f, 0.f, 0.f, 0.f};

  auto stage = [&](int bufi, int kt) {             // 8 loads/thread = full 256x64 A + B
    const int kof = kt * 64;
    #pragma unroll
    for (int r = 0; r < 4; ++r) {
      __builtin_amdgcn_global_load_lds(
          (t_gvoid*)(Abase + (size_t)(r * 64 + rowS) * KPAD + kof + scol),
          (t_lvoid*)&lA[bufi][r * 4096 + wb8], 16, 0, 0);
      __builtin_amdgcn_global_load_lds(
          (t_gvoid*)(Bbase + (size_t)(r * 64 + rowS) * KPAD + kof + scol),
          (t_lvoid*)&lB[bufi][r * 4096 + wb8], 16, 0, 0);
    }
  };

  stage(0, 0);
  for (int kt = 0; kt < NTK; ++kt) {
    const int cur = kt & 1;
    if (kt + 1 < NTK) {
      stage(cur ^ 1, kt + 1);
      asm volatile("s_waitcnt vmcnt(8)" ::: "memory");
    } else {
      asm volatile("s_waitcnt vmcnt(0)" ::: "memory");
    }
    asm volatile("s_barrier" ::: "memory");

    #pragma unroll
    for (int kk = 0; kk < 2; ++kk) {
      bf16x8 af[8], bfr[4];
      #pragma unroll
      for (int mi = 0; mi < 8; ++mi) {
        const int ra = wm * 128 + mi * 16 + lrow;
        af[mi] = *reinterpret_cast<const bf16x8*>(
            &lA[cur][ra * 64 + ((kk * 32 + lgrp * 8) ^ ((ra & 7) * 8))]);
      }
      #pragma unroll
      for (int ni = 0; ni < 4; ++ni) {
        const int rb = wn * 64 + ni * 16 + lrow;
        bfr[ni] = *reinterpret_cast<const bf16x8*>(
            &lB[cur][rb * 64 + ((kk * 32 + lgrp * 8) ^ ((rb & 7) * 8))]);
      }
      #pragma unroll
      for (int mi = 0; mi < 8; ++mi)
        #pragma unroll
        for (int ni = 0; ni < 4; ++ni)
          acc[mi][ni] = __builtin_amdgcn_mfma_f32_16x16x32_bf16(af[mi], bfr[ni],
                                                                acc[mi][ni], 0, 0, 0);
    }
    asm volatile("s_barrier" ::: "memory");
  }

  const int fr_col = lane & 15;
  const int fr_rowb = (lane >> 4) * 4;
  #pragma unroll
  for (int mi = 0; mi < 8; ++mi) {
    const int rowb = mtile * 256 + wm * 128 + mi * 16 + fr_rowb;
    #pragma unroll
    for (int ni = 0; ni < 4; ++ni) {
      const int col = ntile * 256 + wn * 64 + ni * 16 + fr_col;
      #pragma unroll
      for (int r = 0; r < 4; ++r) {
        const int rr = rowb + r;
        if (rr < M) outF[((size_t)b * M + rr) * NN + col] = acc[mi][ni][r] + bias[rr];
      }
    }
  }
}

// ---------------- launch ----------------
extern "C" void kernel_launch(void* const* d_in, const int* in_sizes, int n_in,
                              void* d_out, int out_size, void* d_ws, size_t ws_size,
                              hipStream_t stream) {
  const float* x      = (const float*)d_in[0];
  const float* Wf_pos = (const float*)d_in[1];
  const float* Wd_pos = (const float*)d_in[2];
  const float* g_pos  = (const float*)d_in[3];
  const float* be_pos = (const float*)d_in[4];
  const float* Wf1    = (const float*)d_in[5];
  const float* Wd1    = (const float*)d_in[6];
  const float* g1     = (const float*)d_in[7];
  const float* be1    = (const float*)d_in[8];
  const float* Wf2    = (const float*)d_in[9];
  const float* Wd2    = (const float*)d_in[10];
  const float* g2     = (const float*)d_in[11];
  const float* be2    = (const float*)d_in[12];
  const float* W3     = (const float*)d_in[13];
  const float* g3     = (const float*)d_in[14];
  const float* be3    = (const float*)d_in[15];
  const float* Ws1f   = (const float*)d_in[16];
  const float* Ws1d   = (const float*)d_in[17];
  const float* gs1    = (const float*)d_in[18];
  const float* bs1    = (const float*)d_in[19];
  const float* Ws2f   = (const float*)d_in[20];
  const float* Ws2d   = (const float*)d_in[21];
  const float* gs2    = (const float*)d_in[22];
  const float* bs2    = (const float*)d_in[23];
  const float* Wstd   = (const float*)d_in[24];
  const float* Wt1    = (const float*)d_in[25];
  const float* Wt2    = (const float*)d_in[26];
  const float* Wt3    = (const float*)d_in[27];
  const float* bt3    = (const float*)d_in[28];
  (void)in_sizes; (void)n_in; (void)out_size; (void)ws_size;

  float* out = (float*)d_out;
  float* out_theta = out + 1020;

  char* ws = (char*)d_ws;
  size_t off = 0;
  auto alloc = [&](size_t bytes) -> void* {
    void* p = (void*)(ws + off);
    off += (bytes + 255) & ~(size_t)255;
    return p;
  };
  int*            idx  = (int*)           alloc((size_t)BB * NN * KNB * 4);
  float*          feat = (float*)         alloc((size_t)BB * NN * KNB * 9 * 4);
  float*          stats= (float*)         alloc(1024 * 4);
  float*          part = (float*)         alloc(2048 * 4);
  float*          h1   = (float*)         alloc((size_t)BB * 21 * 3 * NN * 4);
  float*          h2   = (float*)         alloc((size_t)BB * 21 * 3 * NN * 4);
  float*          h3   = (float*)         alloc((size_t)BB * 42 * 3 * NN * 4);
  float*          h4   = (float*)         alloc((size_t)BB * 170 * 3 * NN * 4);
  float*          zbuf = (float*)         alloc((size_t)BB * 170 * 3 * 4);
  float*          pbuf = (float*)         alloc((size_t)BB * 170 * 3 * NN * 4);
  float*          dbuf = (float*)         alloc((size_t)BB * 170 * 3 * NN * 4);
  float*          z0a  = (float*)         alloc((size_t)BB * 170 * 3 * NN * 4);
  float*          z0b  = (float*)         alloc((size_t)BB * 85 * 3 * NN * 4);
  float*          z0f  = (float*)         alloc((size_t)BB * 3 * 3 * NN * 4);
  float*          zbf  = (float*)         alloc((size_t)6 * 170 * 4);
  float*          zbd  = (float*)         alloc((size_t)6 * 170 * 4);
  unsigned short* W1b  = (unsigned short*)alloc((size_t)1024 * KPAD * 2);
  unsigned short* W2b  = (unsigned short*)alloc((size_t)1024 * KPAD * 2);
  unsigned short* W3b  = (unsigned short*)alloc((size_t)MPAD3 * KPAD * 2);
  unsigned short* t0   = (unsigned short*)alloc((size_t)BB * NN * KPAD * 2);
  unsigned short* t1   = (unsigned short*)alloc((size_t)BB * NN * KPAD * 2);
  unsigned short* t2   = t0;   // reuse (t0 dead after GEMM1)

  knn_kernel<<<BB * 512, 256, 0, stream>>>(x, idx);
  feat_kernel<<<(BB * NN * KNB + 255) / 256, 256, 0, stream>>>(x, idx, feat);
  l1_stats_part<<<dim3(21, 8), 256, 0, stream>>>(feat, Wf_pos, part);
  l1_stats_fin<<<1, 64, 0, stream>>>(part, g_pos, stats);
  l1_final_kernel<<<dim3(8, 21, BB), 256, 0, stream>>>(feat, Wf_pos, Wd_pos, stats, be_pos, h1);

  vn_lin_fast<1, 0><<<dim3(8, 2, BB * 3), 256, 0, stream>>>(h1, Wf1, Wd1, nullptr, nullptr, pbuf, dbuf, 21, 21, 21);
  bn_stats_kernel<<<21, 256, 0, stream>>>(pbuf, g1, stats, 21);
  vn_gate_kernel<1><<<dim3(8, 21, BB), 256, 0, stream>>>(pbuf, dbuf, stats, be1, h2, 21, 0.0f);

  vn_lin_fast<1, 0><<<dim3(8, 3, BB * 3), 256, 0, stream>>>(h2, Wf2, Wd2, nullptr, nullptr, pbuf, dbuf, 21, 21, 42);
  bn_stats_kernel<<<42, 256, 0, stream>>>(pbuf, g2, stats, 42);
  vn_gate_kernel<1><<<dim3(8, 42, BB), 256, 0, stream>>>(pbuf, dbuf, stats, be2, h3, 42, 0.0f);

  vn_lin_fast<0, 0><<<dim3(8, 11, BB * 3), 256, 0, stream>>>(h3, W3, nullptr, nullptr, nullptr, pbuf, nullptr, 42, 42, 170);
  bn_stats_kernel<<<170, 256, 0, stream>>>(pbuf, g3, stats, 170);
  vn_gate_kernel<0><<<dim3(8, 170, BB), 256, 0, stream>>>(pbuf, nullptr, stats, be3, h4, 170, 0.0f);

  zmean_kernel<<<dim3(510, BB), 256, 0, stream>>>(h4, zbuf, out);

  zbias_kernel<<<6, 256, 0, stream>>>(zbuf, Ws1f, Ws1d, zbf, zbd, 170, 340, 170);
  vn_lin_fast<1, 1><<<dim3(8, 11, BB * 3), 256, 0, stream>>>(h4, Ws1f, Ws1d, zbf, zbd, pbuf, dbuf, 170, 340, 170);
  bn_stats_kernel<<<170, 256, 0, stream>>>(pbuf, gs1, stats, 170);
  vn_gate_kernel<1><<<dim3(8, 170, BB), 256, 0, stream>>>(pbuf, dbuf, stats, bs1, z0a, 170, 0.2f);

  vn_lin_fast<1, 0><<<dim3(8, 6, BB * 3), 256, 0, stream>>>(z0a, Ws2f, Ws2d, nullptr, nullptr, pbuf, dbuf, 170, 170, 85);
  bn_stats_kernel<<<85, 256, 0, stream>>>(pbuf, gs2, stats, 85);
  vn_gate_kernel<1><<<dim3(8, 85, BB), 256, 0, stream>>>(pbuf, dbuf, stats, bs2, z0b, 85, 0.2f);

  vn_lin_fast<0, 0><<<dim3(8, 1, BB * 3), 256, 0, stream>>>(z0b, Wstd, nullptr, nullptr, nullptr, z0f, nullptr, 85, 85, 3);

  hs_kernel<<<dim3(NN / HST, 1, BB), 256, 0, stream>>>(h4, zbuf, z0f, t0);

  wconv_kernel<<<512, 256, 0, stream>>>(Wt1, W1b, 1020, 1020, (size_t)1024 * KPAD / 8);
  wconv_kernel<<<512, 256, 0, stream>>>(Wt2, W2b, 1020, 1020, (size_t)1024 * KPAD / 8);
  wconv_kernel<<<2048, 256, 0, stream>>>(Wt3, W3b, 14450, 1020, (size_t)MPAD3 * KPAD / 8);

  gemm_kernel<1><<<256, 256, 0, stream>>>(W1b, t0, t1, 1020);
  gemm_kernel<1><<<256, 256, 0, stream>>>(W2b, t1, t2, 1020);
  gemm256_kernel<<<8 * MT3 * BB, 512, 0, stream>>>(W3b, t2, out_theta, bt3, 14450, MT3);
}